// Round 3
// baseline (398.342 us; speedup 1.0000x reference)
//
#include <hip/hip_runtime.h>
#include <stdint.h>

// TopkActivation: per-row top-k (k=64) over H=32768 fp32, scatter into zeros.
// One 512-thread block per row; whole row in registers (64 uints/thread after
// in-place monotonic-key conversion). Radix-select via 4096-bin histogram of
// the top 12 key bits. Winners marked in an LDS bitmap -> exactly ONE global
// store per element, issued dead-last and never awaited in-kernel.
// All barriers are raw lgkmcnt(0)+s_barrier (LDS state only) so neither loads
// nor stores are ever drained at a barrier. 512 threads + <=128 VGPR gives 2
// blocks/CU co-resident: one block streams while the other runs its phases.
// Tie semantics identical to jax.lax.top_k (equal values -> lower index wins).

#define H_DIM    32768
#define NTHREADS 512
#define VPT      (H_DIM / NTHREADS / 4)   // 16 float4 per thread
#define CAP      2048
#define NBINS    4096
#define NWORDS   (H_DIM / 32)             // 1024 bitmap words
#define NWAVES   (NTHREADS / 64)          // 8
#define BPT      (NBINS / NTHREADS)       // 8 bins per thread in scan

typedef float f32x4 __attribute__((ext_vector_type(4)));

__device__ __forceinline__ uint32_t f2mono(float f) {
    uint32_t u = __float_as_uint(f);
    return (u & 0x80000000u) ? ~u : (u | 0x80000000u);
}
__device__ __forceinline__ float mono2f(uint32_t m) {
    uint32_t u = (m & 0x80000000u) ? (m & 0x7fffffffu) : ~m;
    return __uint_as_float(u);
}

// LDS-visibility barrier WITHOUT vmcnt drain: all cross-thread state is LDS.
__device__ __forceinline__ void BAR() {
    asm volatile("s_waitcnt lgkmcnt(0)" ::: "memory");
    __builtin_amdgcn_s_barrier();
}

__global__ __launch_bounds__(NTHREADS, 4)
void topk_kernel(const float* __restrict__ in, const int* __restrict__ kp,
                 float* __restrict__ out)
{
    __shared__ uint32_t hist[NBINS];
    __shared__ uint32_t bitmap[NWORDS];
    __shared__ uint32_t wave_tot[NWAVES];
    __shared__ uint32_t s_b, s_g, s_cnt;
    __shared__ uint32_t s_ncand;
    __shared__ uint32_t cand_u[CAP];
    __shared__ uint32_t cand_i[CAP];

    const uint32_t t   = threadIdx.x;
    const uint32_t row = blockIdx.x;
    const uint32_t k   = (uint32_t)kp[0];

    const f32x4* __restrict__ rin = (const f32x4*)(in + (size_t)row * H_DIM);

    // ---- zero LDS state
    #pragma unroll
    for (int i = 0; i < NBINS / NTHREADS; ++i) hist[t + i * NTHREADS] = 0;
    #pragma unroll
    for (int i = 0; i < NWORDS / NTHREADS; ++i) bitmap[t + i * NTHREADS] = 0;
    if (t == 0) s_ncand = 0;
    BAR();

    // ---- load row -> registers, convert in place to monotonic keys,
    //      histogram top 12 bits (loads all issued up-front; reg deps wait)
    uint32_t um[VPT][4];
    #pragma unroll
    for (int i = 0; i < VPT; ++i) {
        f32x4 v = rin[t + i * NTHREADS];
        um[i][0] = f2mono(v.x);
        um[i][1] = f2mono(v.y);
        um[i][2] = f2mono(v.z);
        um[i][3] = f2mono(v.w);
        atomicAdd(&hist[um[i][0] >> 20], 1u);
        atomicAdd(&hist[um[i][1] >> 20], 1u);
        atomicAdd(&hist[um[i][2] >> 20], 1u);
        atomicAdd(&hist[um[i][3] >> 20], 1u);
    }
    BAR();

    // ---- boundary bin b: cumAbove(b) < k <= cumAbove(b) + hist[b]
    {
        uint32_t h[BPT];
        uint32_t s = 0;
        #pragma unroll
        for (int bb = 0; bb < BPT; ++bb) { h[bb] = hist[BPT * t + bb]; s += h[bb]; }
        const uint32_t lane = t & 63, wid = t >> 6;
        uint32_t v = s;
        #pragma unroll
        for (int off = 1; off < 64; off <<= 1) {      // inclusive suffix scan
            uint32_t o = __shfl_down(v, off);
            if (lane + off < 64) v += o;
        }
        if (lane == 0) wave_tot[wid] = v;
        BAR();
        uint32_t acc = 0;                              // suffix over waves > wid
        #pragma unroll
        for (int w = 0; w < NWAVES; ++w) if ((uint32_t)w > wid) acc += wave_tot[w];
        const uint32_t Ech = v + acc - s;              // strictly-above count
        if (Ech < k && k <= Ech + s) {                 // exactly one thread
            uint32_t gl = Ech;
            #pragma unroll
            for (int bb = BPT - 1; bb >= 0; --bb) {
                if (gl + h[bb] >= k) { s_b = BPT * t + (uint32_t)bb; s_g = gl; s_cnt = h[bb]; break; }
                gl += h[bb];
            }
        }
    }
    BAR();

    uint32_t prefix = s_b;
    uint32_t g      = s_g;
    uint32_t cnt    = s_cnt;
    uint32_t shift  = 20;

    // ---- rare fallback: refine until boundary population fits CAP
    while (cnt > CAP && shift > 0) {
        uint32_t nshift = (shift >= 12) ? (shift - 12) : 0;
        uint32_t nbits  = shift - nshift;
        uint32_t nbins  = 1u << nbits;
        BAR();
        for (uint32_t i = t; i < nbins; i += NTHREADS) hist[i] = 0;
        BAR();
        #pragma unroll
        for (int it = 0; it < VPT; ++it)
            #pragma unroll
            for (int c = 0; c < 4; ++c) {
                uint32_t u = um[it][c];
                if ((u >> shift) == prefix)
                    atomicAdd(&hist[(u >> nshift) & (nbins - 1)], 1u);
            }
        BAR();
        if (t == 0) {
            uint32_t gl = g;
            for (int bb = (int)nbins - 1; bb >= 0; --bb) {
                uint32_t hh = hist[bb];
                if (gl + hh >= k) { s_b = (uint32_t)bb; s_g = gl; s_cnt = hh; break; }
                gl += hh;
            }
        }
        BAR();
        prefix = (prefix << nbits) | s_b;
        g = s_g; cnt = s_cnt; shift = nshift;
    }

    // ---- collect boundary-bin candidates
    const uint32_t need = k - g;
    #pragma unroll
    for (int it = 0; it < VPT; ++it)
        #pragma unroll
        for (int c = 0; c < 4; ++c) {
            uint32_t u = um[it][c];
            if ((u >> shift) == prefix) {
                uint32_t p = atomicAdd(&s_ncand, 1u);
                if (p < CAP) {
                    cand_u[p] = u;
                    cand_i[p] = (t + (uint32_t)it * NTHREADS) * 4u + (uint32_t)c;
                }
            }
        }
    BAR();

    // ---- rank candidates (value desc, index asc); mark winners in bitmap
    {
        uint32_t nc = s_ncand; if (nc > CAP) nc = CAP;
        for (uint32_t i = t; i < nc; i += NTHREADS) {
            uint32_t ui = cand_u[i], ii = cand_i[i];
            uint32_t rank = 0;
            for (uint32_t j = 0; j < nc; ++j) {
                uint32_t uj = cand_u[j];
                rank += (uj > ui || (uj == ui && cand_i[j] < ii)) ? 1u : 0u;
            }
            if (rank < need) atomicOr(&bitmap[ii >> 5], 1u << (ii & 31));
        }
    }
    BAR();

    // ---- single write pass, dead-last; stores never awaited in-kernel
    {
        f32x4* __restrict__ rout = (f32x4*)(out + (size_t)row * H_DIM);
        #pragma unroll
        for (int it = 0; it < VPT; ++it) {
            f32x4 o;
            #pragma unroll
            for (int c = 0; c < 4; ++c) {
                uint32_t u  = um[it][c];
                uint32_t hi = u >> shift;
                float val = 0.0f;
                if (hi > prefix) {
                    val = mono2f(u);
                } else if (hi == prefix) {
                    uint32_t ii = (t + (uint32_t)it * NTHREADS) * 4u + (uint32_t)c;
                    if ((bitmap[ii >> 5] >> (ii & 31)) & 1u) val = mono2f(u);
                }
                o[c] = val;
            }
            __builtin_nontemporal_store(o, &rout[t + it * NTHREADS]);
        }
    }
}

extern "C" void kernel_launch(void* const* d_in, const int* in_sizes, int n_in,
                              void* d_out, int out_size, void* d_ws, size_t ws_size,
                              hipStream_t stream)
{
    const float* x  = (const float*)d_in[0];
    const int*   kp = (const int*)d_in[1];
    float* out = (float*)d_out;
    const int B = in_sizes[0] / H_DIM;
    hipLaunchKernelGGL(topk_kernel, dim3(B), dim3(NTHREADS), 0, stream, x, kp, out);
}

// Round 4
// 359.628 us; speedup vs baseline: 1.1076x; 1.1076x over previous
//
#include <hip/hip_runtime.h>
#include <stdint.h>

// TopkActivation: per-row top-k (k=64) over H=32768 fp32, scatter into zeros.
// One 1024-thread block per row (grid=4096). Row lives in registers as 32
// order-preserving monotonic keys/thread. Radix-select via 4096-bin histogram
// of the top 12 key bits; winners marked in an LDS bitmap -> exactly ONE
// global store per element, issued dead-last and never awaited in-kernel.
// All barriers are raw lgkmcnt(0)+s_barrier (cross-thread state is LDS-only),
// so no vmcnt drain ever: block N's tail stores retire under block N+1's
// loads. __launch_bounds__(1024,8) caps VGPR at 64 -> 2 blocks/CU resident,
// hiding one block's LDS phases under the other block's HBM streaming.
// Tie semantics identical to jax.lax.top_k (equal values -> lower index wins).

#define H_DIM    32768
#define NTHREADS 1024
#define VPT      (H_DIM / NTHREADS / 4)   // 8 float4 per thread -> 32 keys
#define CAP      2048
#define NBINS    4096
#define NWORDS   (H_DIM / 32)             // 1024 bitmap words
#define NWAVES   (NTHREADS / 64)          // 16
#define BPT      (NBINS / NTHREADS)       // 4 bins per thread in scan

typedef float f32x4 __attribute__((ext_vector_type(4)));

__device__ __forceinline__ uint32_t f2mono(float f) {
    uint32_t u = __float_as_uint(f);
    return (u & 0x80000000u) ? ~u : (u | 0x80000000u);
}
__device__ __forceinline__ float mono2f(uint32_t m) {
    uint32_t u = (m & 0x80000000u) ? (m & 0x7fffffffu) : ~m;
    return __uint_as_float(u);
}

// LDS-visibility barrier WITHOUT vmcnt drain: all cross-thread state is LDS.
__device__ __forceinline__ void BAR() {
    asm volatile("s_waitcnt lgkmcnt(0)" ::: "memory");
    __builtin_amdgcn_s_barrier();
}

__global__ __launch_bounds__(NTHREADS, 8)   // 8 waves/EU -> VGPR<=64, 2 blk/CU
void topk_kernel(const float* __restrict__ in, const int* __restrict__ kp,
                 float* __restrict__ out)
{
    __shared__ uint32_t hist[NBINS];
    __shared__ uint32_t bitmap[NWORDS];
    __shared__ uint32_t wave_tot[NWAVES];
    __shared__ uint32_t s_b, s_g, s_cnt;
    __shared__ uint32_t s_ncand;
    __shared__ uint32_t cand_u[CAP];
    __shared__ uint32_t cand_i[CAP];

    const uint32_t t   = threadIdx.x;
    const uint32_t row = blockIdx.x;
    const uint32_t k   = (uint32_t)kp[0];

    const f32x4* __restrict__ rin = (const f32x4*)(in + (size_t)row * H_DIM);

    // ---- zero LDS state
    #pragma unroll
    for (int i = 0; i < NBINS / NTHREADS; ++i) hist[t + i * NTHREADS] = 0;
    bitmap[t] = 0;
    if (t == 0) s_ncand = 0;
    BAR();

    // ---- load row -> registers (monotonic keys, in place) + 12-bit histogram
    uint32_t um[VPT][4];
    #pragma unroll
    for (int i = 0; i < VPT; ++i) {
        f32x4 v = rin[t + i * NTHREADS];
        um[i][0] = f2mono(v.x);
        um[i][1] = f2mono(v.y);
        um[i][2] = f2mono(v.z);
        um[i][3] = f2mono(v.w);
        atomicAdd(&hist[um[i][0] >> 20], 1u);
        atomicAdd(&hist[um[i][1] >> 20], 1u);
        atomicAdd(&hist[um[i][2] >> 20], 1u);
        atomicAdd(&hist[um[i][3] >> 20], 1u);
    }
    BAR();

    // ---- boundary bin b: cumAbove(b) < k <= cumAbove(b) + hist[b]
    {
        uint32_t h[BPT];
        uint32_t s = 0;
        #pragma unroll
        for (int bb = 0; bb < BPT; ++bb) { h[bb] = hist[BPT * t + bb]; s += h[bb]; }
        const uint32_t lane = t & 63, wid = t >> 6;
        uint32_t v = s;
        #pragma unroll
        for (int off = 1; off < 64; off <<= 1) {       // inclusive suffix scan
            uint32_t o = __shfl_down(v, off);
            if (lane + off < 64) v += o;
        }
        if (lane == 0) wave_tot[wid] = v;
        BAR();
        uint32_t acc = 0;                               // suffix over waves > wid
        #pragma unroll
        for (int w = 0; w < NWAVES; ++w) if ((uint32_t)w > wid) acc += wave_tot[w];
        const uint32_t Ech = v + acc - s;               // strictly-above count
        if (Ech < k && k <= Ech + s) {                  // exactly one thread
            uint32_t gl = Ech;
            #pragma unroll
            for (int bb = BPT - 1; bb >= 0; --bb) {
                if (gl + h[bb] >= k) { s_b = BPT * t + (uint32_t)bb; s_g = gl; s_cnt = h[bb]; break; }
                gl += h[bb];
            }
        }
    }
    BAR();

    uint32_t prefix = s_b;
    uint32_t g      = s_g;
    uint32_t cnt    = s_cnt;
    uint32_t shift  = 20;

    // ---- rare fallback: refine until boundary population fits CAP
    while (cnt > CAP && shift > 0) {
        uint32_t nshift = (shift >= 12) ? (shift - 12) : 0;
        uint32_t nbits  = shift - nshift;
        uint32_t nbins  = 1u << nbits;
        BAR();
        for (uint32_t i = t; i < nbins; i += NTHREADS) hist[i] = 0;
        BAR();
        #pragma unroll
        for (int it = 0; it < VPT; ++it)
            #pragma unroll
            for (int c = 0; c < 4; ++c) {
                uint32_t u = um[it][c];
                if ((u >> shift) == prefix)
                    atomicAdd(&hist[(u >> nshift) & (nbins - 1)], 1u);
            }
        BAR();
        if (t == 0) {
            uint32_t gl = g;
            for (int bb = (int)nbins - 1; bb >= 0; --bb) {
                uint32_t hh = hist[bb];
                if (gl + hh >= k) { s_b = (uint32_t)bb; s_g = gl; s_cnt = hh; break; }
                gl += hh;
            }
        }
        BAR();
        prefix = (prefix << nbits) | s_b;
        g = s_g; cnt = s_cnt; shift = nshift;
    }

    // ---- collect boundary-bin candidates
    const uint32_t need = k - g;
    #pragma unroll
    for (int it = 0; it < VPT; ++it)
        #pragma unroll
        for (int c = 0; c < 4; ++c) {
            uint32_t u = um[it][c];
            if ((u >> shift) == prefix) {
                uint32_t p = atomicAdd(&s_ncand, 1u);
                if (p < CAP) {
                    cand_u[p] = u;
                    cand_i[p] = (t + (uint32_t)it * NTHREADS) * 4u + (uint32_t)c;
                }
            }
        }
    BAR();

    // ---- rank candidates (value desc, index asc); mark winners in bitmap
    {
        uint32_t nc = s_ncand; if (nc > CAP) nc = CAP;
        for (uint32_t i = t; i < nc; i += NTHREADS) {
            uint32_t ui = cand_u[i], ii = cand_i[i];
            uint32_t rank = 0;
            for (uint32_t j = 0; j < nc; ++j) {
                uint32_t uj = cand_u[j];
                rank += (uj > ui || (uj == ui && cand_i[j] < ii)) ? 1u : 0u;
            }
            if (rank < need) atomicOr(&bitmap[ii >> 5], 1u << (ii & 31));
        }
    }
    BAR();

    // ---- single write pass, dead-last; stores never awaited in-kernel
    {
        f32x4* __restrict__ rout = (f32x4*)(out + (size_t)row * H_DIM);
        #pragma unroll
        for (int it = 0; it < VPT; ++it) {
            f32x4 o;
            #pragma unroll
            for (int c = 0; c < 4; ++c) {
                uint32_t u  = um[it][c];
                uint32_t hi = u >> shift;
                float val = 0.0f;
                if (hi > prefix) {
                    val = mono2f(u);
                } else if (hi == prefix) {
                    uint32_t ii = (t + (uint32_t)it * NTHREADS) * 4u + (uint32_t)c;
                    if ((bitmap[ii >> 5] >> (ii & 31)) & 1u) val = mono2f(u);
                }
                o[c] = val;
            }
            __builtin_nontemporal_store(o, &rout[t + it * NTHREADS]);
        }
    }
}

extern "C" void kernel_launch(void* const* d_in, const int* in_sizes, int n_in,
                              void* d_out, int out_size, void* d_ws, size_t ws_size,
                              hipStream_t stream)
{
    const float* x  = (const float*)d_in[0];
    const int*   kp = (const int*)d_in[1];
    float* out = (float*)d_out;
    const int B = in_sizes[0] / H_DIM;
    hipLaunchKernelGGL(topk_kernel, dim3(B), dim3(NTHREADS), 0, stream, x, kp, out);
}

// Round 5
// 303.369 us; speedup vs baseline: 1.3131x; 1.1854x over previous
//
#include <hip/hip_runtime.h>
#include <stdint.h>

// TopkActivation: per-row top-k (k=64) over H=32768 fp32, scatter into zeros.
// Two-pass, zero key storage -> low VGPR -> 4 blocks/CU co-resident (stall
// hiding comes from occupancy, not from in-register pipelining):
//   pass A: stream row from HBM, 12-bit LDS histogram of monotonic keys
//   scan:   find boundary bin (cumAbove < k <= cumAbove+bin)
//   pass B: re-read row (Infinity-Cache hit: resident set 256CUx4x128KB=128MB
//           <= 256MB L3), bulk-write value/0, stash boundary candidates
//   fixup:  rank candidates (value desc, index asc), scatter <=64 winner
//           dwords after __syncthreads' vmcnt drain orders the bulk stores.
// Tie semantics identical to jax.lax.top_k (equal values -> lower index wins).

#define H_DIM    32768
#define NTHREADS 512
#define F4PT     (H_DIM / NTHREADS / 4)   // 16 float4 per thread
#define CAP      2048
#define NBINS    4096
#define NWAVES   (NTHREADS / 64)          // 8
#define BPT      (NBINS / NTHREADS)       // 8 bins/thread in scan

typedef float f32x4 __attribute__((ext_vector_type(4)));

__device__ __forceinline__ uint32_t f2mono(float f) {
    uint32_t u = __float_as_uint(f);
    return (u & 0x80000000u) ? ~u : (u | 0x80000000u);
}
__device__ __forceinline__ float mono2f(uint32_t m) {
    uint32_t u = (m & 0x80000000u) ? (m & 0x7fffffffu) : ~m;
    return __uint_as_float(u);
}

__global__ __launch_bounds__(NTHREADS, 8)   // 8 waves/EU -> 4 blocks/CU
void topk_kernel(const float* __restrict__ in, const int* __restrict__ kp,
                 float* __restrict__ out)
{
    __shared__ uint32_t hist[NBINS];
    __shared__ uint32_t wave_tot[NWAVES];
    __shared__ uint32_t s_b, s_g, s_cnt;
    __shared__ uint32_t s_ncand;
    __shared__ uint32_t cand_u[CAP];
    __shared__ uint32_t cand_i[CAP];

    const uint32_t t   = threadIdx.x;
    const uint32_t row = blockIdx.x;
    const uint32_t k   = (uint32_t)kp[0];

    const f32x4* __restrict__ rin = (const f32x4*)(in + (size_t)row * H_DIM);

    // ---- zero LDS
    #pragma unroll
    for (int i = 0; i < NBINS / NTHREADS; ++i) hist[t + i * NTHREADS] = 0;
    if (t == 0) s_ncand = 0;
    __syncthreads();

    // ---- pass A: stream row, 12-bit histogram (no key storage)
    #pragma unroll
    for (int i = 0; i < F4PT; ++i) {
        f32x4 v = rin[t + i * NTHREADS];
        atomicAdd(&hist[f2mono(v.x) >> 20], 1u);
        atomicAdd(&hist[f2mono(v.y) >> 20], 1u);
        atomicAdd(&hist[f2mono(v.z) >> 20], 1u);
        atomicAdd(&hist[f2mono(v.w) >> 20], 1u);
    }
    __syncthreads();

    // ---- boundary bin b: cumAbove(b) < k <= cumAbove(b) + hist[b]
    {
        uint32_t h[BPT];
        uint32_t s = 0;
        #pragma unroll
        for (int bb = 0; bb < BPT; ++bb) { h[bb] = hist[BPT * t + bb]; s += h[bb]; }
        const uint32_t lane = t & 63, wid = t >> 6;
        uint32_t v = s;
        #pragma unroll
        for (int off = 1; off < 64; off <<= 1) {       // inclusive suffix scan
            uint32_t o = __shfl_down(v, off);
            if (lane + off < 64) v += o;
        }
        if (lane == 0) wave_tot[wid] = v;
        __syncthreads();
        uint32_t acc = 0;                               // suffix over waves > wid
        #pragma unroll
        for (int w = 0; w < NWAVES; ++w) if ((uint32_t)w > wid) acc += wave_tot[w];
        const uint32_t Ech = v + acc - s;               // strictly-above count
        if (Ech < k && k <= Ech + s) {                  // exactly one thread
            uint32_t gl = Ech;
            #pragma unroll
            for (int bb = BPT - 1; bb >= 0; --bb) {
                if (gl + h[bb] >= k) { s_b = BPT * t + (uint32_t)bb; s_g = gl; s_cnt = h[bb]; break; }
                gl += h[bb];
            }
        }
    }
    __syncthreads();

    uint32_t prefix = s_b;
    uint32_t g      = s_g;
    uint32_t cnt    = s_cnt;
    uint32_t shift  = 20;

    // ---- rare fallback: refine until boundary population fits CAP
    //      (re-reads row from cache; never triggers for Gaussian data)
    while (cnt > CAP && shift > 0) {
        uint32_t nshift = (shift >= 12) ? (shift - 12) : 0;
        uint32_t nbits  = shift - nshift;
        uint32_t nbins  = 1u << nbits;
        __syncthreads();
        for (uint32_t i = t; i < nbins; i += NTHREADS) hist[i] = 0;
        __syncthreads();
        for (int i = 0; i < F4PT; ++i) {
            f32x4 v = rin[t + i * NTHREADS];
            #pragma unroll
            for (int c = 0; c < 4; ++c) {
                uint32_t u = f2mono(v[c]);
                if ((u >> shift) == prefix)
                    atomicAdd(&hist[(u >> nshift) & (nbins - 1)], 1u);
            }
        }
        __syncthreads();
        if (t == 0) {
            uint32_t gl = g;
            for (int bb = (int)nbins - 1; bb >= 0; --bb) {
                uint32_t hh = hist[bb];
                if (gl + hh >= k) { s_b = (uint32_t)bb; s_g = gl; s_cnt = hh; break; }
                gl += hh;
            }
        }
        __syncthreads();
        prefix = (prefix << nbits) | s_b;
        g = s_g; cnt = s_cnt; shift = nshift;
    }

    // ---- pass B: re-read row (L3-hot), bulk write, stash boundary candidates
    const uint32_t need = k - g;
    {
        f32x4* __restrict__ rout = (f32x4*)(out + (size_t)row * H_DIM);
        #pragma unroll
        for (int i = 0; i < F4PT; ++i) {
            f32x4 v = rin[t + i * NTHREADS];
            f32x4 o;
            #pragma unroll
            for (int c = 0; c < 4; ++c) {
                uint32_t u  = f2mono(v[c]);
                uint32_t hi = u >> shift;
                o[c] = (hi > prefix) ? v[c] : 0.0f;
                if (hi == prefix) {
                    uint32_t p = atomicAdd(&s_ncand, 1u);
                    if (p < CAP) {
                        cand_u[p] = u;
                        cand_i[p] = (t + (uint32_t)i * NTHREADS) * 4u + (uint32_t)c;
                    }
                }
            }
            __builtin_nontemporal_store(o, &rout[t + i * NTHREADS]);
        }
    }
    // vmcnt(0)+lgkmcnt(0) drain: orders bulk stores before winner fix-up and
    // publishes cand_*; co-resident blocks (4/CU) hide the stall.
    __syncthreads();

    // ---- rank candidates (value desc, index asc); scatter <=64 winners
    {
        uint32_t nc = s_ncand; if (nc > CAP) nc = CAP;
        for (uint32_t i = t; i < nc; i += NTHREADS) {
            uint32_t ui = cand_u[i], ii = cand_i[i];
            uint32_t rank = 0;
            for (uint32_t j = 0; j < nc; ++j) {
                uint32_t uj = cand_u[j];
                rank += (uj > ui || (uj == ui && cand_i[j] < ii)) ? 1u : 0u;
            }
            if (rank < need) out[(size_t)row * H_DIM + ii] = mono2f(ui);
        }
    }
}

extern "C" void kernel_launch(void* const* d_in, const int* in_sizes, int n_in,
                              void* d_out, int out_size, void* d_ws, size_t ws_size,
                              hipStream_t stream)
{
    const float* x  = (const float*)d_in[0];
    const int*   kp = (const int*)d_in[1];
    float* out = (float*)d_out;
    const int B = in_sizes[0] / H_DIM;
    hipLaunchKernelGGL(topk_kernel, dim3(B), dim3(NTHREADS), 0, stream, x, kp, out);
}